// Round 1
// baseline (122.786 us; speedup 1.0000x reference)
//
#include <hip/hip_runtime.h>
#include <cstddef>

// Problem constants
#define SS 64
#define NN 128
#define LL 10
#define DD 300
#define HH 150
#define HP 160           // H padded to multiple of 4 floats * 16B-aligned rows

// Workspace layout (in floats)
#define WS_EMB 0                         // S*N*D = 2,457,600 floats
#define WS_SC  (SS*NN*DD)                // S*N   = 8,192 floats
#define WS_W1P (WS_SC + SS*NN)           // D*HP  = 48,000 floats
#define WS_BW  (WS_W1P + DD*HP)          // 2*HP  = 320 floats (b1 pad | W2 pad)

__device__ __forceinline__ void fma4(float4& a, float s, const float4 b) {
    a.x = fmaf(s, b.x, a.x);
    a.y = fmaf(s, b.y, a.y);
    a.z = fmaf(s, b.z, a.z);
    a.w = fmaf(s, b.w, a.w);
}

// ---------------- Kernel 0: pad weights into workspace ----------------
__global__ void pad_weights(const float* __restrict__ W1, const float* __restrict__ b1,
                            const float* __restrict__ W2, float* __restrict__ W1p,
                            float* __restrict__ bW) {
    int idx = blockIdx.x * 256 + threadIdx.x;
    if (idx < DD * HP) {
        int d = idx / HP, j = idx - d * HP;
        W1p[idx] = (j < HH) ? W1[d * HH + j] : 0.f;
    }
    if (idx < HP) {
        bW[idx] = (idx < HH) ? b1[idx] : 0.f;
    } else if (idx < 2 * HP) {
        int j = idx - HP;
        bW[idx] = (j < HH) ? W2[j] : 0.f;
    }
}

// ---------------- Kernel 1: gather embeddings + MLP scores ----------------
// 32 tokens per block, 256 threads.
constexpr int TB = 32;

__global__ __launch_bounds__(256) void k_emb_scores(
        const int* __restrict__ tokens, const float* __restrict__ table,
        const float* __restrict__ W1p, const float* __restrict__ bW,
        const float* __restrict__ b2,
        float* __restrict__ ws_emb, float* __restrict__ ws_sc)
{
    __shared__ float lemb[TB][DD + 4];   // row stride 304 floats (16B aligned)
    __shared__ float lpart[TB][40];      // 38 j-groups used
    __shared__ int   ltok[TB];

    const int tid = threadIdx.x;
    const int t0  = blockIdx.x * TB;

    if (tid < TB) ltok[tid] = tokens[t0 + tid];
    __syncthreads();

    // Gather: 75 float4 per token row; also mirror to ws_emb.
    for (int l = tid; l < TB * 75; l += 256) {
        const int t = l / 75, q = l - t * 75;
        const float4 v = *(const float4*)(table + (size_t)ltok[t] * DD + q * 4);
        *(float4*)&lemb[t][q * 4] = v;
        *(float4*)(ws_emb + (size_t)(t0 + t) * DD + q * 4) = v;
    }
    __syncthreads();

    // MLP: slots = 8 token-groups x 38 j-groups = 304; each slot: 4 tokens x 4 j's.
    for (int slot = tid; slot < 8 * 38; slot += 256) {
        const int tg = slot / 38;
        const int jg = slot - tg * 38;
        const int j0 = jg * 4;
        const int tt = tg * 4;

        float4 acc0 = {0,0,0,0}, acc1 = {0,0,0,0}, acc2 = {0,0,0,0}, acc3 = {0,0,0,0};
        const float* wp = W1p + j0;

        #pragma unroll 5
        for (int d = 0; d < DD; d += 4) {
            const float4 e0 = *(const float4*)&lemb[tt + 0][d];
            const float4 e1 = *(const float4*)&lemb[tt + 1][d];
            const float4 e2 = *(const float4*)&lemb[tt + 2][d];
            const float4 e3 = *(const float4*)&lemb[tt + 3][d];
            const float4 w0 = *(const float4*)(wp + (size_t)(d + 0) * HP);
            const float4 w1 = *(const float4*)(wp + (size_t)(d + 1) * HP);
            const float4 w2 = *(const float4*)(wp + (size_t)(d + 2) * HP);
            const float4 w3 = *(const float4*)(wp + (size_t)(d + 3) * HP);
            fma4(acc0, e0.x, w0); fma4(acc0, e0.y, w1); fma4(acc0, e0.z, w2); fma4(acc0, e0.w, w3);
            fma4(acc1, e1.x, w0); fma4(acc1, e1.y, w1); fma4(acc1, e1.z, w2); fma4(acc1, e1.w, w3);
            fma4(acc2, e2.x, w0); fma4(acc2, e2.y, w1); fma4(acc2, e2.z, w2); fma4(acc2, e2.w, w3);
            fma4(acc3, e3.x, w0); fma4(acc3, e3.y, w1); fma4(acc3, e3.z, w2); fma4(acc3, e3.w, w3);
        }

        const float4 bb = *(const float4*)(bW + j0);        // b1 (padded 0)
        const float4 v2 = *(const float4*)(bW + HP + j0);   // W2 (padded 0)

        #define RELD(A) (fmaxf((A).x + bb.x, 0.f) * v2.x + \
                         fmaxf((A).y + bb.y, 0.f) * v2.y + \
                         fmaxf((A).z + bb.z, 0.f) * v2.z + \
                         fmaxf((A).w + bb.w, 0.f) * v2.w)
        lpart[tt + 0][jg] = RELD(acc0);
        lpart[tt + 1][jg] = RELD(acc1);
        lpart[tt + 2][jg] = RELD(acc2);
        lpart[tt + 3][jg] = RELD(acc3);
        #undef RELD
    }
    __syncthreads();

    // Deterministic reduction over 38 j-groups per token.
    if (tid < TB) {
        float s = 0.f;
        #pragma unroll
        for (int jg = 0; jg < 38; ++jg) s += lpart[tid][jg];
        ws_sc[t0 + tid] = s + b2[0];
    }
}

// ---------------- Kernel 2: window softmax + output assembly ----------------
// One block per (s, i); writes 10*900 = 9000 floats.
__global__ __launch_bounds__(256) void k_out(
        const float* __restrict__ ws_emb, const float* __restrict__ ws_sc,
        float* __restrict__ out)
{
    const int bid = blockIdx.x;          // = s*N + i
    const int i   = bid & (NN - 1);
    const int nk  = min(LL, NN - i);     // number of valid window rows

    __shared__ float le[LL][DD + 4];     // window embeddings, stride 304
    __shared__ float lp[LL][12];         // probs

    const int tid = threadIdx.x;

    // Stage nk contiguous emb rows (rows i..i+nk-1 of this s are contiguous).
    const float* src = ws_emb + (size_t)bid * DD;
    for (int l = tid; l < nk * 75; l += 256) {
        const int k = l / 75, q = l - k * 75;
        *(float4*)&le[k][q * 4] = *(const float4*)(src + l * 4);
    }

    // Softmax rows: thread w handles row w (w < nk). Scores are L2/L1 hot.
    if (tid < nk) {
        const int w = tid;
        const float* scp = ws_sc + bid;  // scp[k] = score at position i+k
        float m = -1e30f;
        for (int k = 0; k <= w; ++k) m = fmaxf(m, scp[k]);
        float sum = 0.f;
        for (int k = 0; k <= w; ++k) {
            const float e = __expf(scp[k] - m);
            lp[w][k] = e;
            sum += e;
        }
        const float inv = 1.f / sum;
        for (int k = 0; k <= w; ++k) lp[w][k] *= inv;
    }
    __syncthreads();

    // Stream the 9000-float output row as 2250 float4 (coalesced).
    float* dst = out + (size_t)bid * (LL * 3 * DD);
    for (int o4 = tid; o4 < (LL * 3 * DD) / 4; o4 += 256) {
        const int w  = o4 / 225;         // 225 float4 per window row
        const int c4 = o4 - w * 225;
        const int c  = c4 * 4;
        float4 v;
        if (w >= nk) {
            v = make_float4(0.f, 0.f, 0.f, 0.f);
        } else if (c < DD) {
            v = *(const float4*)&le[0][c];               // first = emb[i]
        } else if (c < 2 * DD) {
            v = *(const float4*)&le[w][c - DD];          // last = emb[i+w]
        } else {
            const int cc = c - 2 * DD;                   // head = probs @ win_emb
            float4 a = make_float4(0.f, 0.f, 0.f, 0.f);
            for (int k = 0; k <= w; ++k) {
                const float p = lp[w][k];
                fma4(a, p, *(const float4*)&le[k][cc]);
            }
            v = a;
        }
        *(float4*)(dst + (size_t)o4 * 4) = v;
    }
}

// ---------------- Launch ----------------
extern "C" void kernel_launch(void* const* d_in, const int* in_sizes, int n_in,
                              void* d_out, int out_size, void* d_ws, size_t ws_size,
                              hipStream_t stream) {
    const int*   tokens = (const int*)d_in[0];
    const float* table  = (const float*)d_in[1];
    const float* W1     = (const float*)d_in[2];
    const float* b1     = (const float*)d_in[3];
    const float* W2     = (const float*)d_in[4];
    const float* b2     = (const float*)d_in[5];
    float* out = (float*)d_out;
    float* ws  = (float*)d_ws;

    float* ws_emb = ws + WS_EMB;
    float* ws_sc  = ws + WS_SC;
    float* W1p    = ws + WS_W1P;
    float* bW     = ws + WS_BW;

    pad_weights<<<(DD * HP + 255) / 256, 256, 0, stream>>>(W1, b1, W2, W1p, bW);
    k_emb_scores<<<(SS * NN) / TB, 256, 0, stream>>>(tokens, table, W1p, bW, b2, ws_emb, ws_sc);
    k_out<<<SS * NN, 256, 0, stream>>>(ws_emb, ws_sc, out);
}

// Round 2
// 116.478 us; speedup vs baseline: 1.0542x; 1.0542x over previous
//
#include <hip/hip_runtime.h>
#include <cstddef>

// Problem constants
#define SS 64
#define NN 128
#define LL 10
#define DD 300
#define HH 150
#define HP 160           // H padded to 160 (16B-aligned float4 rows)
#define CC 16            // positions per output block
#define RMAX (CC + LL - 1)

// Workspace layout (in floats)
#define WS_SC  0                         // S*N = 8192 floats
#define WS_W1P (WS_SC + SS*NN)           // D*HP = 48000 floats
#define WS_BW  (WS_W1P + DD*HP)          // 2*HP = 320 floats (b1 pad | W2 pad)

__device__ __forceinline__ void fma4(float4& a, float s, const float4 b) {
    a.x = fmaf(s, b.x, a.x);
    a.y = fmaf(s, b.y, a.y);
    a.z = fmaf(s, b.z, a.z);
    a.w = fmaf(s, b.w, a.w);
}

// ---------------- Kernel 0: pad weights into workspace ----------------
__global__ void pad_weights(const float* __restrict__ W1, const float* __restrict__ b1,
                            const float* __restrict__ W2, float* __restrict__ W1p,
                            float* __restrict__ bW) {
    int idx = blockIdx.x * 256 + threadIdx.x;
    if (idx < DD * HP) {
        int d = idx / HP, j = idx - d * HP;
        W1p[idx] = (j < HH) ? W1[d * HH + j] : 0.f;
    }
    if (idx < HP) {
        bW[idx] = (idx < HH) ? b1[idx] : 0.f;
    } else if (idx < 2 * HP) {
        int j = idx - HP;
        bW[idx] = (j < HH) ? W2[j] : 0.f;
    }
}

// ---------------- Kernel 1: gather embeddings + MLP scores ----------------
constexpr int TB = 32;

__global__ __launch_bounds__(256) void k_scores(
        const int* __restrict__ tokens, const float* __restrict__ table,
        const float* __restrict__ W1p, const float* __restrict__ bW,
        const float* __restrict__ b2, float* __restrict__ ws_sc)
{
    __shared__ float lemb[TB][DD + 4];   // row stride 304 floats
    __shared__ float lpart[TB][40];      // 38 j-groups used
    __shared__ int   ltok[TB];

    const int tid = threadIdx.x;
    const int t0  = blockIdx.x * TB;

    if (tid < TB) ltok[tid] = tokens[t0 + tid];
    __syncthreads();

    for (int l = tid; l < TB * 75; l += 256) {
        const int t = l / 75, q = l - t * 75;
        *(float4*)&lemb[t][q * 4] = *(const float4*)(table + (size_t)ltok[t] * DD + q * 4);
    }
    __syncthreads();

    // 8 token-groups x 38 j-groups; each slot: 4 tokens x 4 j's.
    for (int slot = tid; slot < 8 * 38; slot += 256) {
        const int tg = slot / 38;
        const int jg = slot - tg * 38;
        const int j0 = jg * 4;
        const int tt = tg * 4;

        float4 acc0 = {0,0,0,0}, acc1 = {0,0,0,0}, acc2 = {0,0,0,0}, acc3 = {0,0,0,0};
        const float* wp = W1p + j0;

        #pragma unroll 5
        for (int d = 0; d < DD; d += 4) {
            const float4 e0 = *(const float4*)&lemb[tt + 0][d];
            const float4 e1 = *(const float4*)&lemb[tt + 1][d];
            const float4 e2 = *(const float4*)&lemb[tt + 2][d];
            const float4 e3 = *(const float4*)&lemb[tt + 3][d];
            const float4 w0 = *(const float4*)(wp + (size_t)(d + 0) * HP);
            const float4 w1 = *(const float4*)(wp + (size_t)(d + 1) * HP);
            const float4 w2 = *(const float4*)(wp + (size_t)(d + 2) * HP);
            const float4 w3 = *(const float4*)(wp + (size_t)(d + 3) * HP);
            fma4(acc0, e0.x, w0); fma4(acc0, e0.y, w1); fma4(acc0, e0.z, w2); fma4(acc0, e0.w, w3);
            fma4(acc1, e1.x, w0); fma4(acc1, e1.y, w1); fma4(acc1, e1.z, w2); fma4(acc1, e1.w, w3);
            fma4(acc2, e2.x, w0); fma4(acc2, e2.y, w1); fma4(acc2, e2.z, w2); fma4(acc2, e2.w, w3);
            fma4(acc3, e3.x, w0); fma4(acc3, e3.y, w1); fma4(acc3, e3.z, w2); fma4(acc3, e3.w, w3);
        }

        const float4 bb = *(const float4*)(bW + j0);
        const float4 v2 = *(const float4*)(bW + HP + j0);

        #define RELD(A) (fmaxf((A).x + bb.x, 0.f) * v2.x + \
                         fmaxf((A).y + bb.y, 0.f) * v2.y + \
                         fmaxf((A).z + bb.z, 0.f) * v2.z + \
                         fmaxf((A).w + bb.w, 0.f) * v2.w)
        lpart[tt + 0][jg] = RELD(acc0);
        lpart[tt + 1][jg] = RELD(acc1);
        lpart[tt + 2][jg] = RELD(acc2);
        lpart[tt + 3][jg] = RELD(acc3);
        #undef RELD
    }
    __syncthreads();

    if (tid < TB) {
        float s = 0.f;
        #pragma unroll
        for (int jg = 0; jg < 38; ++jg) s += lpart[tid][jg];
        ws_sc[t0 + tid] = s + b2[0];
    }
}

// ---------------- Kernel 2: gather + softmax + output (16 positions/block) ----
__global__ __launch_bounds__(256) void k_out(
        const int* __restrict__ tokens, const float* __restrict__ table,
        const float* __restrict__ ws_sc, float* __restrict__ out)
{
    const int bid = blockIdx.x;          // s*8 + chunk
    const int s   = bid >> 3;
    const int i0  = (bid & 7) * CC;
    const int R   = min(RMAX, NN - i0);  // emb rows staged

    __shared__ float le[RMAX][DD + 4];   // window embeddings, stride 304
    __shared__ float lp[CC][LL][12];     // probs
    __shared__ float sc_l[RMAX];

    const int tid = threadIdx.x;

    if (tid < R) sc_l[tid] = ws_sc[s * NN + i0 + tid];

    const int* tk = tokens + s * NN + i0;
    for (int l = tid; l < R * 75; l += 256) {
        const int k = l / 75, q = l - k * 75;
        *(float4*)&le[k][q * 4] = *(const float4*)(table + (size_t)tk[k] * DD + q * 4);
    }
    __syncthreads();

    // 160 softmax rows, one thread each; 3-pass from LDS (no local arrays).
    if (tid < CC * LL) {
        const int li = tid / LL, w = tid - li * LL;
        const int nk = min(LL, NN - (i0 + li));
        if (w < nk) {
            float m = -1e30f;
            for (int k = 0; k <= w; ++k) m = fmaxf(m, sc_l[li + k]);
            float sum = 0.f;
            for (int k = 0; k <= w; ++k) sum += __expf(sc_l[li + k] - m);
            const float inv = 1.f / sum;
            for (int k = 0; k <= w; ++k) lp[li][w][k] = __expf(sc_l[li + k] - m) * inv;
        }
    }
    __syncthreads();

    // Stream 16*9000 floats = 9000 float4 stores per block, coalesced.
    float* dst = out + (size_t)(s * NN + i0) * (LL * 3 * DD);
    for (int o4 = tid; o4 < CC * 2250; o4 += 256) {
        const int li = o4 / 2250;
        const int r  = o4 - li * 2250;
        const int w  = r / 225;
        const int c4 = r - w * 225;
        const int c  = c4 * 4;
        const int nk = min(LL, NN - (i0 + li));
        float4 v;
        if (w >= nk) {
            v = make_float4(0.f, 0.f, 0.f, 0.f);
        } else if (c < DD) {
            v = *(const float4*)&le[li][c];              // first = emb[i]
        } else if (c < 2 * DD) {
            v = *(const float4*)&le[li + w][c - DD];     // last = emb[i+w]
        } else {
            const int cc = c - 2 * DD;                   // head
            float4 a = make_float4(0.f, 0.f, 0.f, 0.f);
            for (int k = 0; k <= w; ++k) {
                fma4(a, lp[li][w][k], *(const float4*)&le[li + k][cc]);
            }
            v = a;
        }
        *(float4*)(dst + (size_t)o4 * 4) = v;
    }
}

// ---------------- Launch ----------------
extern "C" void kernel_launch(void* const* d_in, const int* in_sizes, int n_in,
                              void* d_out, int out_size, void* d_ws, size_t ws_size,
                              hipStream_t stream) {
    const int*   tokens = (const int*)d_in[0];
    const float* table  = (const float*)d_in[1];
    const float* W1     = (const float*)d_in[2];
    const float* b1     = (const float*)d_in[3];
    const float* W2     = (const float*)d_in[4];
    const float* b2     = (const float*)d_in[5];
    float* out = (float*)d_out;
    float* ws  = (float*)d_ws;

    float* ws_sc = ws + WS_SC;
    float* W1p   = ws + WS_W1P;
    float* bW    = ws + WS_BW;

    pad_weights<<<(DD * HP + 255) / 256, 256, 0, stream>>>(W1, b1, W2, W1p, bW);
    k_scores<<<(SS * NN) / TB, 256, 0, stream>>>(tokens, table, W1p, bW, b2, ws_sc);
    k_out<<<SS * (NN / CC), 256, 0, stream>>>(tokens, table, ws_sc, out);
}